// Round 1
// baseline (413.524 us; speedup 1.0000x reference)
//
#include <hip/hip_runtime.h>

#define NEGF  (-1e30f)
#define LOG2E 1.4426950408889634f
#define LN2F  0.6931471805599453f

// log2-domain logaddexp using native v_exp_f32 (2^x) / v_log_f32 (log2 x)
__device__ __forceinline__ float fexp2(float x) {
#if __has_builtin(__builtin_amdgcn_exp2f)
    return __builtin_amdgcn_exp2f(x);
#else
    return exp2f(x);
#endif
}
__device__ __forceinline__ float flog2(float x) {
#if __has_builtin(__builtin_amdgcn_logf)
    return __builtin_amdgcn_logf(x);
#else
    return log2f(x);
#endif
}
__device__ __forceinline__ float lse2(float a, float b) {
    float m  = fmaxf(a, b);
    float mn = fminf(a, b);
    return m + flog2(1.0f + fexp2(mn - m));
}
__device__ __forceinline__ float lse3(float a, float b, float c) {
    float m = fmaxf(fmaxf(a, b), c);
    float s = fexp2(a - m) + fexp2(b - m) + fexp2(c - m);
    return m + flog2(s);
}

// One wave (64 lanes) per (utterance, direction). Lane i owns extended states
// 4i..4i+3 (S <= 201 <= 256). blockIdx.x <  N : forward alpha scan t=0..tm
//                             blockIdx.x >= N : backward beta  scan t=T-1..tm
// Results (alpha[tm], beta[tm], 256 states each, log2 domain) go to ws.
__global__ __launch_bounds__(64, 1)
void ctc_scan(const float* __restrict__ lp, const int* __restrict__ tgt,
              const int* __restrict__ ilen, const int* __restrict__ tlen,
              float* __restrict__ wsA, float* __restrict__ wsB,
              int T, int N, int C, int L)
{
    const int  b      = blockIdx.x;
    const bool is_fwd = (b < N);
    const int  n      = is_fwd ? b : (b - N);
    const int  lane   = threadIdx.x;
    const int  len_t  = tlen[n];
    const int  len_in = ilen[n];
    const int  tm     = (len_in - 1) >> 1;
    const int  send   = 2 * len_t;           // final blank state index

    const long tb = (long)n * L;
    auto getT = [&](int k) -> int {
        return (k >= 0 && k < len_t) ? tgt[tb + k] : 0;
    };
    const int lm1 = getT(2 * lane - 1);
    const int l1  = getT(2 * lane);      // label of state 4i+1
    const int l2  = getT(2 * lane + 1);  // label of state 4i+3
    const int l3  = getT(2 * lane + 2);  // label of state 4i+5 (lane i+1's l1)
    const int c1 = l1, c3 = l2;
    const bool skip1 = (lane > 0) && (l1 != lm1); // skip_ok[4i+1]
    const bool skip3 = (l2 != l1);                // skip_ok[4i+3]
    const bool skip5 = (l3 != l2);                // skip_ok[4i+5]
    const int  s0 = 4 * lane;
    const bool v0 = (s0     <= send);
    const bool v1 = (s0 + 1 <= send);
    const bool v2 = (s0 + 2 <= send);
    const bool v3 = (s0 + 3 <= send);

    const long   rstride = (long)N * C;
    const float* row0    = lp + (long)n * C;

    constexpr int PF = 16;                 // prefetch depth (steps)
    float peb[PF], pe1[PF], pe3[PF];

    if (is_fwd) {
        // ---- forward alpha ----
        float eb0 = row0[0];
        float e10 = row0[c1];
        float a0 = (lane == 0) ? eb0 * LOG2E : NEGF;
        float a1 = (lane == 0 && 1 <= send) ? e10 * LOG2E : NEGF;
        float a2 = NEGF, a3 = NEGF;

        auto fstep = [&](float ebr, float e1r, float e3r) {
            float eb = ebr * LOG2E, e1 = e1r * LOG2E, e3 = e3r * LOG2E;
            float p3 = __shfl_up(a3, 1, 64);
            p3 = (lane == 0) ? NEGF : p3;              // a[-1] = NEG
            float n0 = lse2(a0, p3) + eb;
            float n1 = lse3(a1, a0, skip1 ? p3 : NEGF) + e1;
            float n2 = lse2(a2, a1) + eb;
            float n3 = lse3(a3, a2, skip3 ? a1 : NEGF) + e3;
            a0 = v0 ? n0 : NEGF;
            a1 = v1 ? n1 : NEGF;
            a2 = v2 ? n2 : NEGF;
            a3 = v3 ? n3 : NEGF;
        };

        const int nsteps = tm;             // steps t = 1..tm
        #pragma unroll
        for (int j = 0; j < PF; ++j) {
            long tt = 1 + j; if (tt > len_in - 1) tt = len_in - 1;
            const float* p = row0 + tt * rstride;
            peb[j] = p[0]; pe1[j] = p[c1]; pe3[j] = p[c3];
        }
        int t = 1;
        while (t + PF - 1 <= nsteps) {
            #pragma unroll
            for (int j = 0; j < PF; ++j) {
                fstep(peb[j], pe1[j], pe3[j]);
                long tt = t + j + PF; if (tt > len_in - 1) tt = len_in - 1;
                const float* p = row0 + tt * rstride;
                peb[j] = p[0]; pe1[j] = p[c1]; pe3[j] = p[c3];
            }
            t += PF;
        }
        {   // tail (< PF steps), slots j hold rows t+j
            const int t0 = t;
            #pragma unroll
            for (int j = 0; j < PF; ++j)
                if (t0 + j <= nsteps) fstep(peb[j], pe1[j], pe3[j]);
        }
        *((float4*)(wsA + (long)n * 256) + lane) = make_float4(a0, a1, a2, a3);
    } else {
        // ---- backward beta ----
        float b0 = (s0     == send || s0     == send - 1) ? 0.0f : NEGF;
        float b1 = (s0 + 1 == send || s0 + 1 == send - 1) ? 0.0f : NEGF;
        float b2 = (s0 + 2 == send || s0 + 2 == send - 1) ? 0.0f : NEGF;
        float b3 = (s0 + 3 == send || s0 + 3 == send - 1) ? 0.0f : NEGF;
        b0 = v0 ? b0 : NEGF; b1 = v1 ? b1 : NEGF;
        b2 = v2 ? b2 : NEGF; b3 = v3 ? b3 : NEGF;

        auto bstep = [&](float ebr, float e1r, float e3r) {
            float eb = ebr * LOG2E, e1 = e1r * LOG2E, e3 = e3r * LOG2E;
            float f0 = b0 + eb;                        // beta[t+1][s'] + E[t+1][s']
            float f1 = b1 + e1;
            float f2 = b2 + eb;
            float f3 = b3 + e3;
            float f0p = __shfl_down(f0, 1, 64);
            float f1p = __shfl_down(f1, 1, 64);
            f0p = (lane == 63) ? NEGF : f0p;
            f1p = (lane == 63) ? NEGF : f1p;
            float n0 = lse2(f0, f1);
            float n1 = lse3(f1, f2, skip3 ? f3 : NEGF);
            float n2 = lse2(f2, f3);
            float n3 = lse3(f3, f0p, skip5 ? f1p : NEGF);
            b0 = v0 ? n0 : NEGF;
            b1 = v1 ? n1 : NEGF;
            b2 = v2 ? n2 : NEGF;
            b3 = v3 ? n3 : NEGF;
        };

        const int nsteps = len_in - 1 - tm; // step k consumes row len_in-1-k
        #pragma unroll
        for (int j = 0; j < PF; ++j) {
            long rr = len_in - 1 - j; if (rr < 0) rr = 0;
            const float* p = row0 + rr * rstride;
            peb[j] = p[0]; pe1[j] = p[c1]; pe3[j] = p[c3];
        }
        int k = 0;
        while (k + PF <= nsteps) {
            #pragma unroll
            for (int j = 0; j < PF; ++j) {
                bstep(peb[j], pe1[j], pe3[j]);
                long rr = len_in - 1 - (k + j + PF); if (rr < 0) rr = 0;
                const float* p = row0 + rr * rstride;
                peb[j] = p[0]; pe1[j] = p[c1]; pe3[j] = p[c3];
            }
            k += PF;
        }
        {
            const int k0 = k;
            #pragma unroll
            for (int j = 0; j < PF; ++j)
                if (k0 + j < nsteps) bstep(peb[j], pe1[j], pe3[j]);
        }
        *((float4*)(wsB + (long)n * 256) + lane) = make_float4(b0, b1, b2, b3);
    }
}

// tot_n = logsumexp_s( alpha[tm][s] + beta[tm][s] );  out += -tot_n if finite
__global__ __launch_bounds__(64, 1)
void ctc_combine(const float* __restrict__ wsA, const float* __restrict__ wsB,
                 float* __restrict__ out)
{
    const int n = blockIdx.x;
    const int lane = threadIdx.x;
    const float4 A = *((const float4*)(wsA + (long)n * 256) + lane);
    const float4 B = *((const float4*)(wsB + (long)n * 256) + lane);
    float v = lse2(lse2(A.x + B.x, A.y + B.y), lse2(A.z + B.z, A.w + B.w));
    #pragma unroll
    for (int off = 1; off < 64; off <<= 1) {
        float o = __shfl_xor(v, off, 64);
        v = lse2(v, o);
    }
    if (lane == 0) {
        float tot = v * LN2F;                 // back to natural log
        if (tot > -1e29f) atomicAdd(out, -tot);
    }
}

extern "C" void kernel_launch(void* const* d_in, const int* in_sizes, int n_in,
                              void* d_out, int out_size, void* d_ws, size_t ws_size,
                              hipStream_t stream) {
    const float* lp      = (const float*)d_in[0];
    const int*   targets = (const int*)d_in[1];
    const int*   in_len  = (const int*)d_in[2];
    const int*   tgt_len = (const int*)d_in[3];
    const int N = in_sizes[2];
    const int L = in_sizes[1] / N;
    const int C = 1024;                       // fixed by the reference problem
    const int T = (int)((long)in_sizes[0] / ((long)N * C));

    float* out = (float*)d_out;
    float* wsA = (float*)d_ws;                // N*256 floats
    float* wsB = wsA + (long)N * 256;         // N*256 floats  (total 64 KB)

    hipMemsetAsync(out, 0, sizeof(float), stream);
    ctc_scan<<<2 * N, 64, 0, stream>>>(lp, targets, in_len, tgt_len,
                                       wsA, wsB, T, N, C, L);
    ctc_combine<<<N, 64, 0, stream>>>(wsA, wsB, out);
}